// Round 1
// baseline (282.873 us; speedup 1.0000x reference)
//
#include <hip/hip_runtime.h>
#include <math.h>

#define B_    2
#define S_    2048
#define DM    512
#define H_    8
#define HD    64
#define PROJ  1544
#define CHK   64
#define NC    (S_/CHK)   // 32
#define BS_   (B_*S_)    // 4096

// ---------------------------------------------------------------------------
// Generic fp32 GEMM:  C[m][n] = sum_k A[m][k] * W[n][k] + bias[n]
// A: M x K row-major, W: N x K row-major (weights as given), 64x64 tile,
// 256 threads, 4x4 accum per thread, K-tile 16.
// ---------------------------------------------------------------------------
__global__ __launch_bounds__(256) void gemm_awt(const float* __restrict__ A,
                                                const float* __restrict__ W,
                                                const float* __restrict__ bias,
                                                float* __restrict__ Cm,
                                                int M, int N, int K) {
    __shared__ float As[16][64];
    __shared__ float Bs[16][64];
    const int tid = threadIdx.x;
    const int tx = tid & 15, ty = tid >> 4;
    const int m0 = blockIdx.y * 64, n0 = blockIdx.x * 64;
    float acc[4][4] = {};

    const int lrow = tid >> 2;        // 0..63
    const int lk   = (tid & 3) * 4;   // 0,4,8,12

    for (int k0 = 0; k0 < K; k0 += 16) {
        float4 av = *(const float4*)&A[(size_t)(m0 + lrow) * K + k0 + lk];
        As[lk + 0][lrow] = av.x; As[lk + 1][lrow] = av.y;
        As[lk + 2][lrow] = av.z; As[lk + 3][lrow] = av.w;
        float4 bv = make_float4(0.f, 0.f, 0.f, 0.f);
        if (n0 + lrow < N)
            bv = *(const float4*)&W[(size_t)(n0 + lrow) * K + k0 + lk];
        Bs[lk + 0][lrow] = bv.x; Bs[lk + 1][lrow] = bv.y;
        Bs[lk + 2][lrow] = bv.z; Bs[lk + 3][lrow] = bv.w;
        __syncthreads();
#pragma unroll
        for (int kk = 0; kk < 16; kk++) {
            float4 a4 = *(const float4*)&As[kk][ty * 4];
            float4 b4 = *(const float4*)&Bs[kk][tx * 4];
            float a[4] = {a4.x, a4.y, a4.z, a4.w};
            float b[4] = {b4.x, b4.y, b4.z, b4.w};
#pragma unroll
            for (int i = 0; i < 4; i++)
#pragma unroll
                for (int j = 0; j < 4; j++)
                    acc[i][j] += a[i] * b[j];
        }
        __syncthreads();
    }
#pragma unroll
    for (int i = 0; i < 4; i++) {
        int m = m0 + ty * 4 + i;
#pragma unroll
        for (int j = 0; j < 4; j++) {
            int n = n0 + tx * 4 + j;
            if (n < N) Cm[(size_t)m * N + n] = acc[i][j] + bias[n];
        }
    }
}

// ---------------------------------------------------------------------------
// Per-chunk KV sums: kvbuf[bh][c][d][t] = sum_{s in chunk} k_s[d] * v_s[t]
// grid = B*H*NC = 512 blocks, 256 threads.
// ---------------------------------------------------------------------------
__global__ __launch_bounds__(256) void chunk_kv(const float* __restrict__ vqkn,
                                                float* __restrict__ kvbuf) {
    __shared__ float Ks[CHK][64];
    __shared__ float Vs[CHK][64];
    const int blk = blockIdx.x;
    const int c  = blk & (NC - 1);
    const int bh = blk >> 5;          // NC == 32
    const int b = bh >> 3, h = bh & 7;
    const int tid = threadIdx.x;
    const int base = b * S_ + c * CHK;

#pragma unroll
    for (int it = 0; it < 16; it++) {
        int idx = it * 256 + tid;     // 0..4095
        int s = idx >> 6, d = idx & 63;
        const float* row = vqkn + (size_t)(base + s) * PROJ;
        Ks[s][d] = row[1024 + h * 64 + d];
        Vs[s][d] = row[h * 64 + d];
    }
    __syncthreads();

    const int col = tid & 63;
    const int rb  = tid >> 6;         // 0..3
    float acc[16] = {};
    for (int s = 0; s < CHK; s++) {
        float v = Vs[s][col];
#pragma unroll
        for (int i = 0; i < 16; i++)
            acc[i] += Ks[s][rb + i * 4] * v;
    }
    float* out = kvbuf + ((size_t)blk << 12);   // blk == bh*NC + c
#pragma unroll
    for (int i = 0; i < 16; i++)
        out[(rb + i * 4) * 64 + col] = acc[i];
}

// ---------------------------------------------------------------------------
// In-place exclusive prefix scan of the 32 chunk states per (b,h).
// grid = B*H = 16 blocks, 256 threads; each thread owns 16 of 4096 elements.
// ---------------------------------------------------------------------------
__global__ __launch_bounds__(256) void scan_kv(float* __restrict__ kvbuf) {
    const int bh = blockIdx.x;
    const int tid = threadIdx.x;
    float run[16] = {};
    float* basep = kvbuf + ((size_t)bh * NC << 12);
    for (int c = 0; c < NC; c++) {
        float* p = basep + ((size_t)c << 12);
#pragma unroll
        for (int i = 0; i < 16; i++) {
            int e = tid + i * 256;
            float cur = p[e];
            p[e] = run[i];
            run[i] += cur;
        }
    }
}

// ---------------------------------------------------------------------------
// Per-chunk attention: O = (Q K^T . causal) V + Q * KVprefix ; gated -> ctx
// grid = B*H*NC = 512 blocks, 256 threads (4 waves x 16 rows each).
// ---------------------------------------------------------------------------
__global__ __launch_bounds__(256) void attn_chunk(const float* __restrict__ vqkn,
                                                  const float* __restrict__ kvbuf,
                                                  float* __restrict__ ctx) {
    __shared__ float Qs[64][64];   // Q[s][d]
    __shared__ float Kt[64][64];   // element (d,t') stored at Kt[d][t' ^ (d&31)]
    __shared__ float Vs[64][64];   // V[t'][t]
    __shared__ float Ps[64][64];   // KVprefix[d][t]
    const int blk = blockIdx.x;
    const int c  = blk & (NC - 1);
    const int bh = blk >> 5;
    const int b = bh >> 3, h = bh & 7;
    const int tid = threadIdx.x;
    const int base = b * S_ + c * CHK;
    const float* kvp = kvbuf + ((size_t)blk << 12);

#pragma unroll
    for (int it = 0; it < 16; it++) {
        int idx = it * 256 + tid;
        int r = idx >> 6, d = idx & 63;
        const float* row = vqkn + (size_t)(base + r) * PROJ;
        Qs[r][d] = row[512 + h * 64 + d];
        Kt[d][r ^ (d & 31)] = row[1024 + h * 64 + d];  // K[r][d] transposed+swizzled
        Vs[r][d] = row[h * 64 + d];
        Ps[r][d] = kvp[idx];                            // P[d][t]: r==d-index, d==t
    }
    __syncthreads();

    const int w = tid >> 6;     // wave id 0..3
    const int lane = tid & 63;
#pragma unroll 1
    for (int rr = 0; rr < 16; rr++) {
        const int s = rr * 4 + w;
        // a(lane=t') = q_s . k_t'  (masked causal, inclusive)
        float a = 0.f;
#pragma unroll
        for (int d = 0; d < 64; d++)
            a += Qs[s][d] * Kt[d][lane ^ (d & 31)];
        if (lane > s) a = 0.f;
        // o(lane=t) = q_s . P[:,t]  +  sum_{t'<=s} a(t') * V[t'][t]
        float o = 0.f;
#pragma unroll
        for (int d = 0; d < 64; d++)
            o += Qs[s][d] * Ps[d][lane];
        for (int t = 0; t <= s; t++) {
            float av = __shfl(a, t, 64);
            o += av * Vs[t][lane];
        }
        float nv = vqkn[(size_t)(base + s) * PROJ + 1536 + h];
        float gate = __expf(-__expf(nv));
        ctx[(size_t)(base + s) * DM + h * 64 + lane] = gate * o;
    }
}

// ---------------------------------------------------------------------------
extern "C" void kernel_launch(void* const* d_in, const int* in_sizes, int n_in,
                              void* d_out, int out_size, void* d_ws, size_t ws_size,
                              hipStream_t stream) {
    const float* x       = (const float*)d_in[0];
    const float* Wvqkn_w = (const float*)d_in[1];
    const float* Wvqkn_b = (const float*)d_in[2];
    const float* out_w   = (const float*)d_in[3];
    const float* out_b   = (const float*)d_in[4];
    float* out = (float*)d_out;

    float* vqkn  = (float*)d_ws;                          // 4096*1544 floats
    float* kvbuf = vqkn + (size_t)BS_ * PROJ;             // 16*32*4096 floats
    float* ctx   = kvbuf + (size_t)B_ * H_ * NC * 4096;   // 4096*512 floats

    // 1) vqkn = x @ W^T + b   (M=4096, N=1544, K=512)
    {
        dim3 grid((PROJ + 63) / 64, BS_ / 64);
        gemm_awt<<<grid, 256, 0, stream>>>(x, Wvqkn_w, Wvqkn_b, vqkn, BS_, PROJ, DM);
    }
    // 2) per-chunk KV sums
    chunk_kv<<<B_ * H_ * NC, 256, 0, stream>>>(vqkn, kvbuf);
    // 3) exclusive prefix scan over chunks
    scan_kv<<<B_ * H_, 256, 0, stream>>>(kvbuf);
    // 4) intra-chunk attention + inter-chunk state + gate
    attn_chunk<<<B_ * H_ * NC, 256, 0, stream>>>(vqkn, kvbuf, ctx);
    // 5) out = ctx @ out_w^T + out_b   (M=4096, N=512, K=512)
    {
        dim3 grid(DM / 64, BS_ / 64);
        gemm_awt<<<grid, 256, 0, stream>>>(ctx, out_w, out_b, out, BS_, DM, DM);
    }
}

// Round 2
// 170.122 us; speedup vs baseline: 1.6628x; 1.6628x over previous
//
#include <hip/hip_runtime.h>
#include <hip/hip_bf16.h>
#include <math.h>

#define B_    2
#define S_    2048
#define DM    512
#define H_    8
#define PROJ  1544
#define NPAD1 1664        // 13*128
#define CHK   64
#define NC    (S_/CHK)    // 32
#define BS_   (B_*S_)     // 4096

typedef __attribute__((ext_vector_type(8))) short shortx8;
typedef __attribute__((ext_vector_type(4))) float floatx4;

#define GCAST(p) ((const __attribute__((address_space(1))) void*)(p))
#define LCAST(p) ((__attribute__((address_space(3))) void*)(p))

__device__ inline short f2bf(float f) {
    __hip_bfloat16 h = __float2bfloat16(f);
    return *(short*)&h;
}

// ---------------------------------------------------------------------------
// fp32 -> bf16 conversion with optional zero row padding (rows beyond srcRows).
// Each thread converts 8 contiguous elements (K==512 is divisible by 8, so a
// thread never straddles a row boundary).
// ---------------------------------------------------------------------------
__global__ __launch_bounds__(256) void convert_pad(const float* __restrict__ src,
                                                   short* __restrict__ dst,
                                                   int srcRows, int dstRows, int K) {
    int t = blockIdx.x * 256 + threadIdx.x;
    long e0 = (long)t * 8;
    if (e0 >= (long)dstRows * K) return;
    int row = (int)(e0 / K);
    short out[8];
    if (row < srcRows) {
        const float* s = src + e0;
        float4 f0 = *(const float4*)s;
        float4 f1 = *(const float4*)(s + 4);
        out[0] = f2bf(f0.x); out[1] = f2bf(f0.y); out[2] = f2bf(f0.z); out[3] = f2bf(f0.w);
        out[4] = f2bf(f1.x); out[5] = f2bf(f1.y); out[6] = f2bf(f1.z); out[7] = f2bf(f1.w);
    } else {
#pragma unroll
        for (int i = 0; i < 8; i++) out[i] = 0;
    }
    *(shortx8*)(dst + e0) = *(shortx8*)out;
}

// ---------------------------------------------------------------------------
// bf16 MFMA GEMM (m97 structure): C[m][n] = sum_k A[m][k]*Bw[n][k] + bias[n]
// A: M x K bf16 (M mult of 128), Bw: Npad x K bf16 (Npad = gridDim.x*128),
// C: fp32, row stride Nstore, col-guarded at Nstore.
// 128x128 tile, BK=32, 256 threads = 4 waves (2x2), 4x4 MFMA frags per wave.
// Staging via global_load_lds width=16.
// ---------------------------------------------------------------------------
__global__ __launch_bounds__(256) void gemm_mfma(const short* __restrict__ A,
                                                 const short* __restrict__ Bw,
                                                 const float* __restrict__ bias,
                                                 float* __restrict__ C,
                                                 int Nstore, int K) {
    __shared__ short As[128 * 32];
    __shared__ short Bs[128 * 32];
    const int tid  = threadIdx.x;
    const int wave = tid >> 6, lane = tid & 63;
    const int m0 = blockIdx.y * 128;
    const int n0 = blockIdx.x * 128;
    const int srow  = tid >> 2;        // 0..63 staging row within 64-row half
    const int skoff = (tid & 3) * 8;   // bf16 offset within 32-wide K tile
    const int lm = lane & 15, q = lane >> 4;
    const int wr = (wave >> 1) * 64, wc = (wave & 1) * 64;
    floatx4 acc[4][4] = {};

    const short* gA0 = A  + (size_t)(m0 + srow) * K + skoff;
    const short* gA1 = A  + (size_t)(m0 + 64 + srow) * K + skoff;
    const short* gB0 = Bw + (size_t)(n0 + srow) * K + skoff;
    const short* gB1 = Bw + (size_t)(n0 + 64 + srow) * K + skoff;

    for (int k0 = 0; k0 < K; k0 += 32) {
        __builtin_amdgcn_global_load_lds(GCAST(gA0 + k0), LCAST(&As[wave * 512]),        16, 0, 0);
        __builtin_amdgcn_global_load_lds(GCAST(gA1 + k0), LCAST(&As[2048 + wave * 512]), 16, 0, 0);
        __builtin_amdgcn_global_load_lds(GCAST(gB0 + k0), LCAST(&Bs[wave * 512]),        16, 0, 0);
        __builtin_amdgcn_global_load_lds(GCAST(gB1 + k0), LCAST(&Bs[2048 + wave * 512]), 16, 0, 0);
        __syncthreads();

        shortx8 af[4], bw[4];
#pragma unroll
        for (int i = 0; i < 4; i++)
            af[i] = *(const shortx8*)&As[(wr + i * 16 + lm) * 32 + q * 8];
#pragma unroll
        for (int j = 0; j < 4; j++)
            bw[j] = *(const shortx8*)&Bs[(wc + j * 16 + lm) * 32 + q * 8];
#pragma unroll
        for (int i = 0; i < 4; i++)
#pragma unroll
            for (int j = 0; j < 4; j++)
                acc[i][j] = __builtin_amdgcn_mfma_f32_16x16x32_bf16(af[i], bw[j], acc[i][j], 0, 0, 0);
        __syncthreads();
    }

    // C/D layout: col = lane&15, row = q*4 + reg  [m89/m91-verified]
#pragma unroll
    for (int i = 0; i < 4; i++) {
        int rb = m0 + wr + i * 16 + q * 4;
#pragma unroll
        for (int j = 0; j < 4; j++) {
            int col = n0 + wc + j * 16 + lm;
            if (col < Nstore) {
                float bv = bias[col];
#pragma unroll
                for (int r = 0; r < 4; r++)
                    C[(size_t)(rb + r) * Nstore + col] = acc[i][j][r] + bv;
            }
        }
    }
}

// ---------------------------------------------------------------------------
// Per-chunk KV sums: kvbuf[bh][c][d][t] = sum_{s in chunk} k_s[d] * v_s[t]
// ---------------------------------------------------------------------------
__global__ __launch_bounds__(256) void chunk_kv(const float* __restrict__ vqkn,
                                                float* __restrict__ kvbuf) {
    __shared__ float Ks[CHK][64];
    __shared__ float Vs[CHK][64];
    const int blk = blockIdx.x;
    const int c  = blk & (NC - 1);
    const int bh = blk >> 5;
    const int b = bh >> 3, h = bh & 7;
    const int tid = threadIdx.x;
    const int base = b * S_ + c * CHK;

#pragma unroll
    for (int it = 0; it < 16; it++) {
        int idx = it * 256 + tid;
        int s = idx >> 6, d = idx & 63;
        const float* row = vqkn + (size_t)(base + s) * PROJ;
        Ks[s][d] = row[1024 + h * 64 + d];
        Vs[s][d] = row[h * 64 + d];
    }
    __syncthreads();

    const int col = tid & 63;
    const int rb  = tid >> 6;
    float acc[16] = {};
    for (int s = 0; s < CHK; s++) {
        float v = Vs[s][col];
#pragma unroll
        for (int i = 0; i < 16; i++)
            acc[i] += Ks[s][rb + i * 4] * v;
    }
    float* out = kvbuf + ((size_t)blk << 12);
#pragma unroll
    for (int i = 0; i < 16; i++)
        out[(rb + i * 4) * 64 + col] = acc[i];
}

// ---------------------------------------------------------------------------
// Exclusive prefix scan over the 32 chunk states per (b,h).
// grid = B*H*16 = 256 blocks; each thread owns ONE of the 4096 state elements.
// ---------------------------------------------------------------------------
__global__ __launch_bounds__(256) void scan_kv(float* __restrict__ kvbuf) {
    const int blk = blockIdx.x;
    const int bh = blk >> 4, seg = blk & 15;
    const int e = seg * 256 + threadIdx.x;
    float* p = kvbuf + (((size_t)bh * NC) << 12) + e;
    float run = 0.f;
#pragma unroll 4
    for (int c = 0; c < NC; c++) {
        float cur = p[(size_t)c << 12];
        p[(size_t)c << 12] = run;
        run += cur;
    }
}

// ---------------------------------------------------------------------------
// Per-chunk attention: O = (Q K^T . causal) V + Q * KVprefix ; gate -> bf16 ctx
// ---------------------------------------------------------------------------
__global__ __launch_bounds__(256) void attn_chunk(const float* __restrict__ vqkn,
                                                  const float* __restrict__ kvbuf,
                                                  short* __restrict__ ctxb) {
    __shared__ float Qs[64][64];
    __shared__ float Kt[64][64];
    __shared__ float Vs[64][64];
    __shared__ float Ps[64][64];
    const int blk = blockIdx.x;
    const int c  = blk & (NC - 1);
    const int bh = blk >> 5;
    const int b = bh >> 3, h = bh & 7;
    const int tid = threadIdx.x;
    const int base = b * S_ + c * CHK;
    const float* kvp = kvbuf + ((size_t)blk << 12);

#pragma unroll
    for (int it = 0; it < 16; it++) {
        int idx = it * 256 + tid;
        int r = idx >> 6, d = idx & 63;
        const float* row = vqkn + (size_t)(base + r) * PROJ;
        Qs[r][d] = row[512 + h * 64 + d];
        Kt[d][r ^ (d & 31)] = row[1024 + h * 64 + d];
        Vs[r][d] = row[h * 64 + d];
        Ps[r][d] = kvp[idx];
    }
    __syncthreads();

    const int w = tid >> 6;
    const int lane = tid & 63;
#pragma unroll 1
    for (int rr = 0; rr < 16; rr++) {
        const int s = rr * 4 + w;
        float a = 0.f;
#pragma unroll
        for (int d = 0; d < 64; d++)
            a += Qs[s][d] * Kt[d][lane ^ (d & 31)];
        if (lane > s) a = 0.f;
        float o = 0.f;
#pragma unroll
        for (int d = 0; d < 64; d++)
            o += Qs[s][d] * Ps[d][lane];
        for (int t = 0; t <= s; t++) {
            float av = __shfl(a, t, 64);
            o += av * Vs[t][lane];
        }
        float nv = vqkn[(size_t)(base + s) * PROJ + 1536 + h];
        float gate = __expf(-__expf(nv));
        ctxb[(size_t)(base + s) * DM + h * 64 + lane] = f2bf(gate * o);
    }
}

// ---------------------------------------------------------------------------
extern "C" void kernel_launch(void* const* d_in, const int* in_sizes, int n_in,
                              void* d_out, int out_size, void* d_ws, size_t ws_size,
                              hipStream_t stream) {
    const float* x       = (const float*)d_in[0];
    const float* Wvqkn_w = (const float*)d_in[1];
    const float* Wvqkn_b = (const float*)d_in[2];
    const float* out_w   = (const float*)d_in[3];
    const float* out_b   = (const float*)d_in[4];
    float* out = (float*)d_out;

    float* vqkn  = (float*)d_ws;                          // 4096*1544 f32
    float* kvbuf = vqkn + (size_t)BS_ * PROJ;             // 16*32*4096 f32
    short* xb    = (short*)(kvbuf + (size_t)B_ * H_ * NC * 4096); // 4096*512 bf16
    short* w1b   = xb  + (size_t)BS_ * DM;                // 1664*512 bf16 (padded)
    short* w2b   = w1b + (size_t)NPAD1 * DM;              // 512*512 bf16
    short* ctxb  = w2b + (size_t)DM * DM;                 // 4096*512 bf16

    // 0) fp32 -> bf16 conversions (+ zero-pad W1 rows 1544..1663)
    convert_pad<<<(BS_ * DM / 8 + 255) / 256, 256, 0, stream>>>(x, xb, BS_, BS_, DM);
    convert_pad<<<(NPAD1 * DM / 8 + 255) / 256, 256, 0, stream>>>(Wvqkn_w, w1b, PROJ, NPAD1, DM);
    convert_pad<<<(DM * DM / 8 + 255) / 256, 256, 0, stream>>>(out_w, w2b, DM, DM, DM);

    // 1) vqkn = x @ W^T + b   (M=4096, Npad=1664, K=512)
    gemm_mfma<<<dim3(NPAD1 / 128, BS_ / 128), 256, 0, stream>>>(xb, w1b, Wvqkn_b, vqkn, PROJ, DM);

    // 2) per-chunk KV sums
    chunk_kv<<<B_ * H_ * NC, 256, 0, stream>>>(vqkn, kvbuf);
    // 3) exclusive prefix scan over chunks
    scan_kv<<<B_ * H_ * 16, 256, 0, stream>>>(kvbuf);
    // 4) intra-chunk attention + inter-chunk state + gate -> bf16 ctx
    attn_chunk<<<B_ * H_ * NC, 256, 0, stream>>>(vqkn, kvbuf, ctxb);

    // 5) out = ctx @ out_w^T + out_b   (M=4096, N=512, K=512)
    gemm_mfma<<<dim3(DM / 128, BS_ / 128), 256, 0, stream>>>(ctxb, w2b, out_b, out, DM, DM);
}

// Round 3
// 125.912 us; speedup vs baseline: 2.2466x; 1.3511x over previous
//
#include <hip/hip_runtime.h>
#include <hip/hip_bf16.h>
#include <math.h>

#define B_    2
#define S_    2048
#define DM    512
#define H_    8
#define PROJ  1544
#define NPAD1 1664        // 13*128
#define CHK   64
#define NC    32
#define BS_   4096
#define BH    16

typedef __attribute__((ext_vector_type(8))) short shortx8;
typedef __attribute__((ext_vector_type(4))) short shortx4;
typedef __attribute__((ext_vector_type(4))) float floatx4;

#define GCAST(p) ((const __attribute__((address_space(1))) void*)(p))
#define LCAST(p) ((__attribute__((address_space(3))) void*)(p))

__device__ inline short f2bf(float f) {
    __hip_bfloat16 h = __float2bfloat16(f);
    return *(short*)&h;
}
__device__ inline float bf2f(short s) {
    __hip_bfloat16 h = *(__hip_bfloat16*)&s;
    return __bfloat162float(h);
}
// Read 8 contiguous bf16 (k multiple of 8) from a 64x64 tile whose 16B groups
// are XOR-swizzled by row: element (row,k) lives at group (k>>3)^(row&7).
__device__ inline shortx8 read8(const short* buf, int row, int k) {
    return *(const shortx8*)&buf[row * 64 + ((((k >> 3) ^ (row & 7))) << 3)];
}

// ---------------------------------------------------------------------------
// fp32 -> bf16 conversion with zero row padding beyond srcRows.
// ---------------------------------------------------------------------------
__global__ __launch_bounds__(256) void convert_pad(const float* __restrict__ src,
                                                   short* __restrict__ dst,
                                                   int srcRows, int dstRows, int K) {
    int t = blockIdx.x * 256 + threadIdx.x;
    long e0 = (long)t * 8;
    if (e0 >= (long)dstRows * K) return;
    int row = (int)(e0 / K);
    short out[8];
    if (row < srcRows) {
        const float* s = src + e0;
        float4 f0 = *(const float4*)s;
        float4 f1 = *(const float4*)(s + 4);
        out[0] = f2bf(f0.x); out[1] = f2bf(f0.y); out[2] = f2bf(f0.z); out[3] = f2bf(f0.w);
        out[4] = f2bf(f1.x); out[5] = f2bf(f1.y); out[6] = f2bf(f1.z); out[7] = f2bf(f1.w);
    } else {
#pragma unroll
        for (int i = 0; i < 8; i++) out[i] = 0;
    }
    *(shortx8*)(dst + e0) = *(shortx8*)out;
}

// ---------------------------------------------------------------------------
// Generic bf16 MFMA GEMM (m97 structure) — used for the output projection.
// ---------------------------------------------------------------------------
__global__ __launch_bounds__(256) void gemm_mfma(const short* __restrict__ A,
                                                 const short* __restrict__ Bw,
                                                 const float* __restrict__ bias,
                                                 float* __restrict__ C,
                                                 int Nstore, int K) {
    __shared__ short As[128 * 32];
    __shared__ short Bs[128 * 32];
    const int tid  = threadIdx.x;
    const int wave = tid >> 6, lane = tid & 63;
    const int m0 = blockIdx.y * 128;
    const int n0 = blockIdx.x * 128;
    const int srow  = tid >> 2;
    const int skoff = (tid & 3) * 8;
    const int lm = lane & 15, q = lane >> 4;
    const int wr = (wave >> 1) * 64, wc = (wave & 1) * 64;
    floatx4 acc[4][4] = {};

    const short* gA0 = A  + (size_t)(m0 + srow) * K + skoff;
    const short* gA1 = A  + (size_t)(m0 + 64 + srow) * K + skoff;
    const short* gB0 = Bw + (size_t)(n0 + srow) * K + skoff;
    const short* gB1 = Bw + (size_t)(n0 + 64 + srow) * K + skoff;

    for (int k0 = 0; k0 < K; k0 += 32) {
        __builtin_amdgcn_global_load_lds(GCAST(gA0 + k0), LCAST(&As[wave * 512]),        16, 0, 0);
        __builtin_amdgcn_global_load_lds(GCAST(gA1 + k0), LCAST(&As[2048 + wave * 512]), 16, 0, 0);
        __builtin_amdgcn_global_load_lds(GCAST(gB0 + k0), LCAST(&Bs[wave * 512]),        16, 0, 0);
        __builtin_amdgcn_global_load_lds(GCAST(gB1 + k0), LCAST(&Bs[2048 + wave * 512]), 16, 0, 0);
        __syncthreads();

        shortx8 af[4], bw[4];
#pragma unroll
        for (int i = 0; i < 4; i++)
            af[i] = *(const shortx8*)&As[(wr + i * 16 + lm) * 32 + q * 8];
#pragma unroll
        for (int j = 0; j < 4; j++)
            bw[j] = *(const shortx8*)&Bs[(wc + j * 16 + lm) * 32 + q * 8];
#pragma unroll
        for (int i = 0; i < 4; i++)
#pragma unroll
            for (int j = 0; j < 4; j++)
                acc[i][j] = __builtin_amdgcn_mfma_f32_16x16x32_bf16(af[i], bw[j], acc[i][j], 0, 0, 0);
        __syncthreads();
    }
#pragma unroll
    for (int i = 0; i < 4; i++) {
        int rb = m0 + wr + i * 16 + q * 4;
#pragma unroll
        for (int j = 0; j < 4; j++) {
            int col = n0 + wc + j * 16 + lm;
            if (col < Nstore) {
                float bv = bias[col];
#pragma unroll
                for (int r = 0; r < 4; r++)
                    C[(size_t)(rb + r) * Nstore + col] = acc[i][j][r] + bv;
            }
        }
    }
}

// ---------------------------------------------------------------------------
// gemm1 with fused epilogue: writes q[bh][s][d], k[bh][t][d], kT[bh][d][s],
// vT[bh][v][s] (all bf16) and gate[bh][s]=exp(-exp(n+b)) fp32.
// ---------------------------------------------------------------------------
__global__ __launch_bounds__(256) void gemm1_fused(const short* __restrict__ A,
                                                   const short* __restrict__ Bw,
                                                   const float* __restrict__ bias,
                                                   short* __restrict__ qb,
                                                   short* __restrict__ kb,
                                                   short* __restrict__ kTb,
                                                   short* __restrict__ vTb,
                                                   float* __restrict__ gateb) {
    __shared__ short As[128 * 32];
    __shared__ short Bs[128 * 32];
    const int K = DM;
    const int tid  = threadIdx.x;
    const int wave = tid >> 6, lane = tid & 63;
    const int m0 = blockIdx.y * 128;
    const int n0 = blockIdx.x * 128;
    const int srow  = tid >> 2;
    const int skoff = (tid & 3) * 8;
    const int lm = lane & 15, q = lane >> 4;
    const int wr = (wave >> 1) * 64, wc = (wave & 1) * 64;
    floatx4 acc[4][4] = {};

    const short* gA0 = A  + (size_t)(m0 + srow) * K + skoff;
    const short* gA1 = A  + (size_t)(m0 + 64 + srow) * K + skoff;
    const short* gB0 = Bw + (size_t)(n0 + srow) * K + skoff;
    const short* gB1 = Bw + (size_t)(n0 + 64 + srow) * K + skoff;

    for (int k0 = 0; k0 < K; k0 += 32) {
        __builtin_amdgcn_global_load_lds(GCAST(gA0 + k0), LCAST(&As[wave * 512]),        16, 0, 0);
        __builtin_amdgcn_global_load_lds(GCAST(gA1 + k0), LCAST(&As[2048 + wave * 512]), 16, 0, 0);
        __builtin_amdgcn_global_load_lds(GCAST(gB0 + k0), LCAST(&Bs[wave * 512]),        16, 0, 0);
        __builtin_amdgcn_global_load_lds(GCAST(gB1 + k0), LCAST(&Bs[2048 + wave * 512]), 16, 0, 0);
        __syncthreads();

        shortx8 af[4], bw[4];
#pragma unroll
        for (int i = 0; i < 4; i++)
            af[i] = *(const shortx8*)&As[(wr + i * 16 + lm) * 32 + q * 8];
#pragma unroll
        for (int j = 0; j < 4; j++)
            bw[j] = *(const shortx8*)&Bs[(wc + j * 16 + lm) * 32 + q * 8];
#pragma unroll
        for (int i = 0; i < 4; i++)
#pragma unroll
            for (int j = 0; j < 4; j++)
                acc[i][j] = __builtin_amdgcn_mfma_f32_16x16x32_bf16(af[i], bw[j], acc[i][j], 0, 0, 0);
        __syncthreads();
    }

    const int bIdx = m0 >> 11;           // batch (blocks never straddle b)
    const int bh0  = bIdx * H_;
#pragma unroll
    for (int i = 0; i < 4; i++) {
        int s0 = (m0 & (S_ - 1)) + wr + i * 16 + q * 4;   // token within batch
#pragma unroll
        for (int j = 0; j < 4; j++) {
            int col = n0 + wc + j * 16 + lm;
            float bv = (col < PROJ) ? bias[col] : 0.f;
            float vals[4];
#pragma unroll
            for (int r = 0; r < 4; r++) vals[r] = acc[i][j][r] + bv;
            if (col < 512) {                       // v -> vT[bh][v][s]
                int h = col >> 6, vd = col & 63;
                short tmp[4];
#pragma unroll
                for (int r = 0; r < 4; r++) tmp[r] = f2bf(vals[r]);
                *(shortx4*)&vTb[((size_t)(bh0 + h) * 64 + vd) * S_ + s0] = *(shortx4*)tmp;
            } else if (col < 1024) {               // q -> q[bh][s][d]
                int h = (col >> 6) - 8, d = col & 63;
                size_t rb = ((size_t)(bh0 + h) * S_ + s0) * 64 + d;
#pragma unroll
                for (int r = 0; r < 4; r++) qb[rb + (size_t)r * 64] = f2bf(vals[r]);
            } else if (col < 1536) {               // k -> k[bh][t][d] and kT[bh][d][t]
                int h = (col >> 6) - 16, d = col & 63;
                size_t rb = ((size_t)(bh0 + h) * S_ + s0) * 64 + d;
                short tmp[4];
#pragma unroll
                for (int r = 0; r < 4; r++) { tmp[r] = f2bf(vals[r]); kb[rb + (size_t)r * 64] = tmp[r]; }
                *(shortx4*)&kTb[((size_t)(bh0 + h) * 64 + d) * S_ + s0] = *(shortx4*)tmp;
            } else if (col < PROJ) {               // n -> gate[bh][s]
                int h = col - 1536;
                float g[4];
#pragma unroll
                for (int r = 0; r < 4; r++) g[r] = __expf(-__expf(vals[r]));
                *(float4*)&gateb[(size_t)(bh0 + h) * S_ + s0] = make_float4(g[0], g[1], g[2], g[3]);
            }
        }
    }
}

// ---------------------------------------------------------------------------
// Per-chunk state via MFMA: U[v][d] = sum_{s in chunk} V[s][v] * K[s][d]
// A-frag = vT[v][s], B-frag = kT[d][s]. 512 blocks.
// ---------------------------------------------------------------------------
__global__ __launch_bounds__(256) void chunk_kv_mfma(const short* __restrict__ vTb,
                                                     const short* __restrict__ kTb,
                                                     float* __restrict__ kvbuf) {
    __shared__ __align__(16) short VT[64 * 64];
    __shared__ __align__(16) short KT[64 * 64];
    const int blk = blockIdx.x;
    const int c = blk & (NC - 1), bh = blk >> 5;
    const int base = c * CHK;
    const int tid = threadIdx.x, wave = tid >> 6, lane = tid & 63;
    const int lrow = lane >> 3, lgrp = lane & 7;

#pragma unroll
    for (int half = 0; half < 2; half++) {
        int v0 = wave * 8 + half * 32;
        int row = v0 + lrow;
        int gcol = ((lgrp ^ (row & 7)) << 3);
        __builtin_amdgcn_global_load_lds(GCAST(vTb + ((size_t)(bh * 64 + row)) * S_ + base + gcol),
                                         LCAST(&VT[v0 * 64]), 16, 0, 0);
        __builtin_amdgcn_global_load_lds(GCAST(kTb + ((size_t)(bh * 64 + row)) * S_ + base + gcol),
                                         LCAST(&KT[v0 * 64]), 16, 0, 0);
    }
    __syncthreads();

    const int lm = lane & 15, q = lane >> 4;
    const int wr = (wave >> 1) * 32, wc = (wave & 1) * 32;
    floatx4 acc[2][2] = {};
#pragma unroll
    for (int ks = 0; ks < 2; ks++) {
        shortx8 a[2], b2[2];
#pragma unroll
        for (int i = 0; i < 2; i++) a[i]  = read8(VT, wr + i * 16 + lm, ks * 32 + q * 8);
#pragma unroll
        for (int j = 0; j < 2; j++) b2[j] = read8(KT, wc + j * 16 + lm, ks * 32 + q * 8);
#pragma unroll
        for (int i = 0; i < 2; i++)
#pragma unroll
            for (int j = 0; j < 2; j++)
                acc[i][j] = __builtin_amdgcn_mfma_f32_16x16x32_bf16(a[i], b2[j], acc[i][j], 0, 0, 0);
    }
    float* outp = kvbuf + ((size_t)blk << 12);
#pragma unroll
    for (int i = 0; i < 2; i++)
#pragma unroll
        for (int j = 0; j < 2; j++)
#pragma unroll
            for (int r = 0; r < 4; r++)
                outp[(wr + i * 16 + q * 4 + r) * 64 + wc + j * 16 + lm] = acc[i][j][r];
}

// ---------------------------------------------------------------------------
// Exclusive prefix scan over 32 chunk states per (b,h). 256 blocks.
// ---------------------------------------------------------------------------
__global__ __launch_bounds__(256) void scan_kv(float* __restrict__ kvbuf) {
    const int blk = blockIdx.x;
    const int bh = blk >> 4, seg = blk & 15;
    const int e = seg * 256 + threadIdx.x;
    float* p = kvbuf + (((size_t)bh * NC) << 12) + e;
    float run = 0.f;
#pragma unroll 4
    for (int c = 0; c < NC; c++) {
        float cur = p[(size_t)c << 12];
        p[(size_t)c << 12] = run;
        run += cur;
    }
}

// ---------------------------------------------------------------------------
// MFMA attention chunk: S = QK^T (causal), O = S.V + Q.P (P split bf16 hi+lo),
// ctx = gate * O. 512 blocks, 4 waves each owning a 32x32 quadrant.
// ---------------------------------------------------------------------------
__global__ __launch_bounds__(256) void attn_mfma(const short* __restrict__ qb,
                                                 const short* __restrict__ kb,
                                                 const short* __restrict__ vTb,
                                                 const float* __restrict__ gateb,
                                                 const float* __restrict__ kvbuf,
                                                 short* __restrict__ ctxb) {
    __shared__ __align__(16) short Qs[64 * 64];
    __shared__ __align__(16) short Ks[64 * 64];
    __shared__ __align__(16) short VTs[64 * 64];
    __shared__ __align__(16) short Phi[64 * 64];
    __shared__ __align__(16) short Plo[64 * 64];
    __shared__ __align__(16) short Sb[64 * 72];   // [s][t], stride 72 (pad)
    __shared__ float gs[64];
    const int blk = blockIdx.x;
    const int c = blk & (NC - 1), bh = blk >> 5;
    const int base = c * CHK;
    const int tid = threadIdx.x, wave = tid >> 6, lane = tid & 63;
    const int lrow = lane >> 3, lgrp = lane & 7;

#pragma unroll
    for (int half = 0; half < 2; half++) {
        int v0 = wave * 8 + half * 32;
        int row = v0 + lrow;
        int gcol = ((lgrp ^ (row & 7)) << 3);
        __builtin_amdgcn_global_load_lds(GCAST(qb + ((size_t)bh * S_ + base + row) * 64 + gcol),
                                         LCAST(&Qs[v0 * 64]), 16, 0, 0);
        __builtin_amdgcn_global_load_lds(GCAST(kb + ((size_t)bh * S_ + base + row) * 64 + gcol),
                                         LCAST(&Ks[v0 * 64]), 16, 0, 0);
        __builtin_amdgcn_global_load_lds(GCAST(vTb + ((size_t)(bh * 64 + row)) * S_ + base + gcol),
                                         LCAST(&VTs[v0 * 64]), 16, 0, 0);
    }
    // stage prefix state P[v][d] fp32 -> bf16 hi/lo (swizzled)
    const float* kvp = kvbuf + ((size_t)blk << 12);
#pragma unroll
    for (int it = 0; it < 16; it++) {
        int idx = it * 256 + tid;
        int v = idx >> 6, d = idx & 63;
        float f = kvp[idx];
        short hi = f2bf(f);
        short lo = f2bf(f - bf2f(hi));
        int sw = v * 64 + (((d >> 3) ^ (v & 7)) << 3) + (d & 7);
        Phi[sw] = hi; Plo[sw] = lo;
    }
    if (tid < 64) gs[tid] = gateb[(size_t)bh * S_ + base + tid];
    __syncthreads();

    const int lm = lane & 15, q = lane >> 4;
    const int wr = (wave >> 1) * 32, wc = (wave & 1) * 32;

    // Phase 1: S quadrant = Q K^T, causal mask, -> Sb bf16
    floatx4 sacc[2][2] = {};
#pragma unroll
    for (int ks = 0; ks < 2; ks++) {
        shortx8 qa[2], kf[2];
#pragma unroll
        for (int i = 0; i < 2; i++) qa[i] = read8(Qs, wr + i * 16 + lm, ks * 32 + q * 8);
#pragma unroll
        for (int j = 0; j < 2; j++) kf[j] = read8(Ks, wc + j * 16 + lm, ks * 32 + q * 8);
#pragma unroll
        for (int i = 0; i < 2; i++)
#pragma unroll
            for (int j = 0; j < 2; j++)
                sacc[i][j] = __builtin_amdgcn_mfma_f32_16x16x32_bf16(qa[i], kf[j], sacc[i][j], 0, 0, 0);
    }
#pragma unroll
    for (int i = 0; i < 2; i++)
#pragma unroll
        for (int j = 0; j < 2; j++)
#pragma unroll
            for (int r = 0; r < 4; r++) {
                int s = wr + i * 16 + q * 4 + r;
                int t = wc + j * 16 + lm;
                Sb[s * 72 + t] = f2bf(t <= s ? sacc[i][j][r] : 0.f);
            }
    __syncthreads();

    // Phase 2: O = S.V + Q.(Phi+Plo)
    floatx4 oacc[2][2] = {};
#pragma unroll
    for (int ks = 0; ks < 2; ks++) {
        shortx8 sa[2], vb[2];
#pragma unroll
        for (int i = 0; i < 2; i++)
            sa[i] = *(const shortx8*)&Sb[(wr + i * 16 + lm) * 72 + ks * 32 + q * 8];
#pragma unroll
        for (int j = 0; j < 2; j++) vb[j] = read8(VTs, wc + j * 16 + lm, ks * 32 + q * 8);
#pragma unroll
        for (int i = 0; i < 2; i++)
#pragma unroll
            for (int j = 0; j < 2; j++)
                oacc[i][j] = __builtin_amdgcn_mfma_f32_16x16x32_bf16(sa[i], vb[j], oacc[i][j], 0, 0, 0);
    }
#pragma unroll
    for (int ks = 0; ks < 2; ks++) {
        shortx8 qa[2], ph[2], pl[2];
#pragma unroll
        for (int i = 0; i < 2; i++) qa[i] = read8(Qs, wr + i * 16 + lm, ks * 32 + q * 8);
#pragma unroll
        for (int j = 0; j < 2; j++) {
            ph[j] = read8(Phi, wc + j * 16 + lm, ks * 32 + q * 8);
            pl[j] = read8(Plo, wc + j * 16 + lm, ks * 32 + q * 8);
        }
#pragma unroll
        for (int i = 0; i < 2; i++)
#pragma unroll
            for (int j = 0; j < 2; j++) {
                oacc[i][j] = __builtin_amdgcn_mfma_f32_16x16x32_bf16(qa[i], ph[j], oacc[i][j], 0, 0, 0);
                oacc[i][j] = __builtin_amdgcn_mfma_f32_16x16x32_bf16(qa[i], pl[j], oacc[i][j], 0, 0, 0);
            }
    }
    // Epilogue: gate * O -> ctx[token][h*64+v] bf16
    const size_t tok0 = (size_t)(bh >> 3) * S_ + base;
    const int h = bh & 7;
#pragma unroll
    for (int i = 0; i < 2; i++)
#pragma unroll
        for (int j = 0; j < 2; j++)
#pragma unroll
            for (int r = 0; r < 4; r++) {
                int s = wr + i * 16 + q * 4 + r;
                int v = wc + j * 16 + lm;
                ctxb[(tok0 + s) * DM + h * 64 + v] = f2bf(gs[s] * oacc[i][j][r]);
            }
}

// ---------------------------------------------------------------------------
extern "C" void kernel_launch(void* const* d_in, const int* in_sizes, int n_in,
                              void* d_out, int out_size, void* d_ws, size_t ws_size,
                              hipStream_t stream) {
    const float* x       = (const float*)d_in[0];
    const float* Wvqkn_w = (const float*)d_in[1];
    const float* Wvqkn_b = (const float*)d_in[2];
    const float* out_w   = (const float*)d_in[3];
    const float* out_b   = (const float*)d_in[4];
    float* out = (float*)d_out;

    float* kvbuf = (float*)d_ws;                          // 16*32*4096 f32
    short* xb    = (short*)(kvbuf + (size_t)BH * NC * 4096);
    short* w1b   = xb   + (size_t)BS_ * DM;
    short* w2b   = w1b  + (size_t)NPAD1 * DM;
    short* ctxb  = w2b  + (size_t)DM * DM;
    short* qb    = ctxb + (size_t)BS_ * DM;
    short* kb    = qb   + (size_t)BH * S_ * 64;
    short* kTb   = kb   + (size_t)BH * S_ * 64;
    short* vTb   = kTb  + (size_t)BH * S_ * 64;
    float* gateb = (float*)(vTb + (size_t)BH * S_ * 64);

    convert_pad<<<(BS_ * DM / 8 + 255) / 256, 256, 0, stream>>>(x, xb, BS_, BS_, DM);
    convert_pad<<<(NPAD1 * DM / 8 + 255) / 256, 256, 0, stream>>>(Wvqkn_w, w1b, PROJ, NPAD1, DM);
    convert_pad<<<(DM * DM / 8 + 255) / 256, 256, 0, stream>>>(out_w, w2b, DM, DM, DM);

    gemm1_fused<<<dim3(NPAD1 / 128, BS_ / 128), 256, 0, stream>>>(
        xb, w1b, Wvqkn_b, qb, kb, kTb, vTb, gateb);

    chunk_kv_mfma<<<BH * NC, 256, 0, stream>>>(vTb, kTb, kvbuf);
    scan_kv<<<BH * 16, 256, 0, stream>>>(kvbuf);
    attn_mfma<<<BH * NC, 256, 0, stream>>>(qb, kb, vTb, gateb, kvbuf, ctxb);

    gemm_mfma<<<dim3(DM / 128, BS_ / 128), 256, 0, stream>>>(ctxb, w2b, out_b, out, DM, DM);
}

// Round 4
// 121.183 us; speedup vs baseline: 2.3343x; 1.0390x over previous
//
#include <hip/hip_runtime.h>
#include <hip/hip_bf16.h>
#include <math.h>

#define B_    2
#define S_    2048
#define DM    512
#define H_    8
#define PROJ  1544
#define NPAD1 1664        // 13*128
#define CHK   64
#define NC    32
#define BS_   4096
#define BH    16

typedef __attribute__((ext_vector_type(8))) short shortx8;
typedef __attribute__((ext_vector_type(4))) short shortx4;
typedef __attribute__((ext_vector_type(4))) float floatx4;

#define GCAST(p) ((const __attribute__((address_space(1))) void*)(p))
#define LCAST(p) ((__attribute__((address_space(3))) void*)(p))

__device__ inline short f2bf(float f) {
    __hip_bfloat16 h = __float2bfloat16(f);
    return *(short*)&h;
}
__device__ inline float bf2f(short s) {
    __hip_bfloat16 h = *(__hip_bfloat16*)&s;
    return __bfloat162float(h);
}
// Read 8 contiguous bf16 (k mult of 8) from a 64x64 tile whose 16B groups are
// XOR-swizzled by row: element (row,k) lives at group (k>>3)^(row&7).
__device__ inline shortx8 read8(const short* buf, int row, int k) {
    return *(const shortx8*)&buf[row * 64 + ((((k >> 3) ^ (row & 7))) << 3)];
}

// ---------------------------------------------------------------------------
// One fused fp32->bf16 convert for x, W1 (zero row-pad to NPAD1), W2.
// 8 contiguous elems per thread; all segment sizes divisible by 8.
// ---------------------------------------------------------------------------
#define E1 ((size_t)BS_ * DM)
#define E2 ((size_t)NPAD1 * DM)
#define E3 ((size_t)DM * DM)
__global__ __launch_bounds__(256) void convert_all(const float* __restrict__ x,
                                                   const float* __restrict__ w1,
                                                   const float* __restrict__ w2,
                                                   short* __restrict__ xb,
                                                   short* __restrict__ w1b,
                                                   short* __restrict__ w2b) {
    size_t e = ((size_t)blockIdx.x * 256 + threadIdx.x) * 8;
    const float* src;
    short* dst;
    bool zero = false;
    if (e < E1) { src = x + e; dst = xb + e; }
    else if (e < E1 + E2) {
        size_t o = e - E1;
        dst = w1b + o;
        size_t row = o >> 9;            // /512
        if (row < PROJ) src = w1 + o; else { src = w1; zero = true; }
    } else if (e < E1 + E2 + E3) {
        size_t o = e - E1 - E2;
        src = w2 + o; dst = w2b + o;
    } else return;
    short out[8];
    if (zero) {
#pragma unroll
        for (int i = 0; i < 8; i++) out[i] = 0;
    } else {
        float4 f0 = *(const float4*)src;
        float4 f1 = *(const float4*)(src + 4);
        out[0] = f2bf(f0.x); out[1] = f2bf(f0.y); out[2] = f2bf(f0.z); out[3] = f2bf(f0.w);
        out[4] = f2bf(f1.x); out[5] = f2bf(f1.y); out[6] = f2bf(f1.z); out[7] = f2bf(f1.w);
    }
    *(shortx8*)dst = *(shortx8*)out;
}

// ---------------------------------------------------------------------------
// 64x128-tile bf16 MFMA GEMM: C[m][n] = sum_k A[m][k]*Bw[n][k] + bias[n].
// 256 threads = 4 waves, each wave owns all 64 rows x 32 cols (wc = wave*32).
// grid = (N/128, M/64). LDS 12KB -> ~5 blocks/CU.
// ---------------------------------------------------------------------------
__global__ __launch_bounds__(256) void gemm_mfma64(const short* __restrict__ A,
                                                   const short* __restrict__ Bw,
                                                   const float* __restrict__ bias,
                                                   float* __restrict__ C,
                                                   int N, int K) {
    __shared__ short As[64 * 32];
    __shared__ short Bs[128 * 32];
    const int tid  = threadIdx.x;
    const int wave = tid >> 6, lane = tid & 63;
    const int m0 = blockIdx.y * 64;
    const int n0 = blockIdx.x * 128;
    const int srow  = lane >> 2;        // 0..15
    const int skoff = (lane & 3) * 8;
    const int lm = lane & 15, q = lane >> 4;
    const int wc = wave * 32;
    floatx4 acc[4][2] = {};

    const short* gA  = A  + (size_t)(m0 + wave * 16 + srow) * K + skoff;
    const short* gB0 = Bw + (size_t)(n0 + wave * 16 + srow) * K + skoff;
    const short* gB1 = Bw + (size_t)(n0 + 64 + wave * 16 + srow) * K + skoff;

    for (int k0 = 0; k0 < K; k0 += 32) {
        __builtin_amdgcn_global_load_lds(GCAST(gA  + k0), LCAST(&As[wave * 512]),        16, 0, 0);
        __builtin_amdgcn_global_load_lds(GCAST(gB0 + k0), LCAST(&Bs[wave * 512]),        16, 0, 0);
        __builtin_amdgcn_global_load_lds(GCAST(gB1 + k0), LCAST(&Bs[2048 + wave * 512]), 16, 0, 0);
        __syncthreads();
        shortx8 af[4], bw[2];
#pragma unroll
        for (int i = 0; i < 4; i++)
            af[i] = *(const shortx8*)&As[(i * 16 + lm) * 32 + q * 8];
#pragma unroll
        for (int j = 0; j < 2; j++)
            bw[j] = *(const shortx8*)&Bs[(wc + j * 16 + lm) * 32 + q * 8];
#pragma unroll
        for (int i = 0; i < 4; i++)
#pragma unroll
            for (int j = 0; j < 2; j++)
                acc[i][j] = __builtin_amdgcn_mfma_f32_16x16x32_bf16(af[i], bw[j], acc[i][j], 0, 0, 0);
        __syncthreads();
    }
#pragma unroll
    for (int i = 0; i < 4; i++) {
        int rb = m0 + i * 16 + q * 4;
#pragma unroll
        for (int j = 0; j < 2; j++) {
            int col = n0 + wc + j * 16 + lm;
            float bv = bias[col];
#pragma unroll
            for (int r = 0; r < 4; r++)
                C[(size_t)(rb + r) * N + col] = acc[i][j][r] + bv;
        }
    }
}

// ---------------------------------------------------------------------------
// gemm1 (64x128 tiles) with fused epilogue: q[bh][s][d], k[bh][t][d],
// kT[bh][d][s], vT[bh][v][s] (bf16), gate[bh][s]=exp(-exp(n+b)) fp32.
// ---------------------------------------------------------------------------
__global__ __launch_bounds__(256) void gemm1_fused(const short* __restrict__ A,
                                                   const short* __restrict__ Bw,
                                                   const float* __restrict__ bias,
                                                   short* __restrict__ qb,
                                                   short* __restrict__ kb,
                                                   short* __restrict__ kTb,
                                                   short* __restrict__ vTb,
                                                   float* __restrict__ gateb) {
    __shared__ short As[64 * 32];
    __shared__ short Bs[128 * 32];
    const int K = DM;
    const int tid  = threadIdx.x;
    const int wave = tid >> 6, lane = tid & 63;
    const int m0 = blockIdx.y * 64;
    const int n0 = blockIdx.x * 128;
    const int srow  = lane >> 2;
    const int skoff = (lane & 3) * 8;
    const int lm = lane & 15, q = lane >> 4;
    const int wc = wave * 32;
    floatx4 acc[4][2] = {};

    const short* gA  = A  + (size_t)(m0 + wave * 16 + srow) * K + skoff;
    const short* gB0 = Bw + (size_t)(n0 + wave * 16 + srow) * K + skoff;
    const short* gB1 = Bw + (size_t)(n0 + 64 + wave * 16 + srow) * K + skoff;

    for (int k0 = 0; k0 < K; k0 += 32) {
        __builtin_amdgcn_global_load_lds(GCAST(gA  + k0), LCAST(&As[wave * 512]),        16, 0, 0);
        __builtin_amdgcn_global_load_lds(GCAST(gB0 + k0), LCAST(&Bs[wave * 512]),        16, 0, 0);
        __builtin_amdgcn_global_load_lds(GCAST(gB1 + k0), LCAST(&Bs[2048 + wave * 512]), 16, 0, 0);
        __syncthreads();
        shortx8 af[4], bw[2];
#pragma unroll
        for (int i = 0; i < 4; i++)
            af[i] = *(const shortx8*)&As[(i * 16 + lm) * 32 + q * 8];
#pragma unroll
        for (int j = 0; j < 2; j++)
            bw[j] = *(const shortx8*)&Bs[(wc + j * 16 + lm) * 32 + q * 8];
#pragma unroll
        for (int i = 0; i < 4; i++)
#pragma unroll
            for (int j = 0; j < 2; j++)
                acc[i][j] = __builtin_amdgcn_mfma_f32_16x16x32_bf16(af[i], bw[j], acc[i][j], 0, 0, 0);
        __syncthreads();
    }

    const int bIdx = m0 >> 11;
    const int bh0  = bIdx * H_;
#pragma unroll
    for (int i = 0; i < 4; i++) {
        int s0 = (m0 & (S_ - 1)) + i * 16 + q * 4;
#pragma unroll
        for (int j = 0; j < 2; j++) {
            int col = n0 + wc + j * 16 + lm;
            float bv = (col < PROJ) ? bias[col] : 0.f;
            float vals[4];
#pragma unroll
            for (int r = 0; r < 4; r++) vals[r] = acc[i][j][r] + bv;
            if (col < 512) {                       // v -> vT[bh][v][s]
                int h = col >> 6, vd = col & 63;
                short tmp[4];
#pragma unroll
                for (int r = 0; r < 4; r++) tmp[r] = f2bf(vals[r]);
                *(shortx4*)&vTb[((size_t)(bh0 + h) * 64 + vd) * S_ + s0] = *(shortx4*)tmp;
            } else if (col < 1024) {               // q -> q[bh][s][d]
                int h = (col >> 6) - 8, d = col & 63;
                size_t rb = ((size_t)(bh0 + h) * S_ + s0) * 64 + d;
#pragma unroll
                for (int r = 0; r < 4; r++) qb[rb + (size_t)r * 64] = f2bf(vals[r]);
            } else if (col < 1536) {               // k -> k[bh][t][d] and kT[bh][d][t]
                int h = (col >> 6) - 16, d = col & 63;
                size_t rb = ((size_t)(bh0 + h) * S_ + s0) * 64 + d;
                short tmp[4];
#pragma unroll
                for (int r = 0; r < 4; r++) { tmp[r] = f2bf(vals[r]); kb[rb + (size_t)r * 64] = tmp[r]; }
                *(shortx4*)&kTb[((size_t)(bh0 + h) * 64 + d) * S_ + s0] = *(shortx4*)tmp;
            } else if (col < PROJ) {               // n -> gate[bh][s]
                int h = col - 1536;
                float g[4];
#pragma unroll
                for (int r = 0; r < 4; r++) g[r] = __expf(-__expf(vals[r]));
                *(float4*)&gateb[(size_t)(bh0 + h) * S_ + s0] = make_float4(g[0], g[1], g[2], g[3]);
            }
        }
    }
}

// ---------------------------------------------------------------------------
// Per-chunk state via MFMA: U[v][d] = sum_{s in chunk} V[s][v] * K[s][d]
// ---------------------------------------------------------------------------
__global__ __launch_bounds__(256) void chunk_kv_mfma(const short* __restrict__ vTb,
                                                     const short* __restrict__ kTb,
                                                     float* __restrict__ kvbuf) {
    __shared__ __align__(16) short VT[64 * 64];
    __shared__ __align__(16) short KT[64 * 64];
    const int blk = blockIdx.x;
    const int c = blk & (NC - 1), bh = blk >> 5;
    const int base = c * CHK;
    const int tid = threadIdx.x, wave = tid >> 6, lane = tid & 63;
    const int lrow = lane >> 3, lgrp = lane & 7;

#pragma unroll
    for (int half = 0; half < 2; half++) {
        int v0 = wave * 8 + half * 32;
        int row = v0 + lrow;
        int gcol = ((lgrp ^ (row & 7)) << 3);
        __builtin_amdgcn_global_load_lds(GCAST(vTb + ((size_t)(bh * 64 + row)) * S_ + base + gcol),
                                         LCAST(&VT[v0 * 64]), 16, 0, 0);
        __builtin_amdgcn_global_load_lds(GCAST(kTb + ((size_t)(bh * 64 + row)) * S_ + base + gcol),
                                         LCAST(&KT[v0 * 64]), 16, 0, 0);
    }
    __syncthreads();

    const int lm = lane & 15, q = lane >> 4;
    const int wr = (wave >> 1) * 32, wc = (wave & 1) * 32;
    floatx4 acc[2][2] = {};
#pragma unroll
    for (int ks = 0; ks < 2; ks++) {
        shortx8 a[2], b2[2];
#pragma unroll
        for (int i = 0; i < 2; i++) a[i]  = read8(VT, wr + i * 16 + lm, ks * 32 + q * 8);
#pragma unroll
        for (int j = 0; j < 2; j++) b2[j] = read8(KT, wc + j * 16 + lm, ks * 32 + q * 8);
#pragma unroll
        for (int i = 0; i < 2; i++)
#pragma unroll
            for (int j = 0; j < 2; j++)
                acc[i][j] = __builtin_amdgcn_mfma_f32_16x16x32_bf16(a[i], b2[j], acc[i][j], 0, 0, 0);
    }
    float* outp = kvbuf + ((size_t)blk << 12);
#pragma unroll
    for (int i = 0; i < 2; i++)
#pragma unroll
        for (int j = 0; j < 2; j++)
#pragma unroll
            for (int r = 0; r < 4; r++)
                outp[(wr + i * 16 + q * 4 + r) * 64 + wc + j * 16 + lm] = acc[i][j][r];
}

// ---------------------------------------------------------------------------
// MFMA attention chunk with self-computed prefix (no scan kernel):
// P = sum_{c'<c} U_{c'} (fp32, from kvbuf); S = QK^T causal; O = S.V + Q.P.
// Block mapping puts heavy (large-c) chunks first.
// ---------------------------------------------------------------------------
__global__ __launch_bounds__(256) void attn_mfma(const short* __restrict__ qb,
                                                 const short* __restrict__ kb,
                                                 const short* __restrict__ vTb,
                                                 const float* __restrict__ gateb,
                                                 const float* __restrict__ kvbuf,
                                                 short* __restrict__ ctxb) {
    __shared__ __align__(16) short Qs[64 * 64];
    __shared__ __align__(16) short Ks[64 * 64];
    __shared__ __align__(16) short VTs[64 * 64];
    __shared__ __align__(16) short Phi[64 * 64];
    __shared__ __align__(16) short Plo[64 * 64];
    __shared__ __align__(16) short Sb[64 * 72];
    __shared__ float gs[64];
    const int blk = blockIdx.x;
    const int bh = blk & (BH - 1);
    const int c  = (NC - 1) - (blk >> 4);     // heavy chunks dispatched first
    const int base = c * CHK;
    const int tid = threadIdx.x, wave = tid >> 6, lane = tid & 63;
    const int lrow = lane >> 3, lgrp = lane & 7;

#pragma unroll
    for (int half = 0; half < 2; half++) {
        int v0 = wave * 8 + half * 32;
        int row = v0 + lrow;
        int gcol = ((lgrp ^ (row & 7)) << 3);
        __builtin_amdgcn_global_load_lds(GCAST(qb + ((size_t)bh * S_ + base + row) * 64 + gcol),
                                         LCAST(&Qs[v0 * 64]), 16, 0, 0);
        __builtin_amdgcn_global_load_lds(GCAST(kb + ((size_t)bh * S_ + base + row) * 64 + gcol),
                                         LCAST(&Ks[v0 * 64]), 16, 0, 0);
        __builtin_amdgcn_global_load_lds(GCAST(vTb + ((size_t)(bh * 64 + row)) * S_ + base + gcol),
                                         LCAST(&VTs[v0 * 64]), 16, 0, 0);
    }

    // Own prefix: P = sum_{c'<c} U_{c'}; each thread owns 16 of 4096 elems.
    float pacc[16] = {};
    {
        const float* kvb = kvbuf + (((size_t)bh * NC) << 12) + tid;
        for (int cp = 0; cp < c; cp++) {
            const float* p = kvb + ((size_t)cp << 12);
#pragma unroll
            for (int it = 0; it < 16; it++) pacc[it] += p[it * 256];
        }
    }
#pragma unroll
    for (int it = 0; it < 16; it++) {
        int idx = it * 256 + tid;
        int v = idx >> 6, d = idx & 63;
        float f = pacc[it];
        short hi = f2bf(f);
        short lo = f2bf(f - bf2f(hi));
        int sw = v * 64 + (((d >> 3) ^ (v & 7)) << 3) + (d & 7);
        Phi[sw] = hi; Plo[sw] = lo;
    }
    if (tid < 64) gs[tid] = gateb[(size_t)bh * S_ + base + tid];
    __syncthreads();

    const int lm = lane & 15, q = lane >> 4;
    const int wr = (wave >> 1) * 32, wc = (wave & 1) * 32;

    // Phase 1: S quadrant = Q K^T, causal mask, -> Sb bf16
    floatx4 sacc[2][2] = {};
#pragma unroll
    for (int ks = 0; ks < 2; ks++) {
        shortx8 qa[2], kf[2];
#pragma unroll
        for (int i = 0; i < 2; i++) qa[i] = read8(Qs, wr + i * 16 + lm, ks * 32 + q * 8);
#pragma unroll
        for (int j = 0; j < 2; j++) kf[j] = read8(Ks, wc + j * 16 + lm, ks * 32 + q * 8);
#pragma unroll
        for (int i = 0; i < 2; i++)
#pragma unroll
            for (int j = 0; j < 2; j++)
                sacc[i][j] = __builtin_amdgcn_mfma_f32_16x16x32_bf16(qa[i], kf[j], sacc[i][j], 0, 0, 0);
    }
#pragma unroll
    for (int i = 0; i < 2; i++)
#pragma unroll
        for (int j = 0; j < 2; j++)
#pragma unroll
            for (int r = 0; r < 4; r++) {
                int s = wr + i * 16 + q * 4 + r;
                int t = wc + j * 16 + lm;
                Sb[s * 72 + t] = f2bf(t <= s ? sacc[i][j][r] : 0.f);
            }
    __syncthreads();

    // Phase 2: O = S.V + Q.(Phi+Plo)
    floatx4 oacc[2][2] = {};
#pragma unroll
    for (int ks = 0; ks < 2; ks++) {
        shortx8 sa[2], vb[2];
#pragma unroll
        for (int i = 0; i < 2; i++)
            sa[i] = *(const shortx8*)&Sb[(wr + i * 16 + lm) * 72 + ks * 32 + q * 8];
#pragma unroll
        for (int j = 0; j < 2; j++) vb[j] = read8(VTs, wc + j * 16 + lm, ks * 32 + q * 8);
#pragma unroll
        for (int i = 0; i < 2; i++)
#pragma unroll
            for (int j = 0; j < 2; j++)
                oacc[i][j] = __builtin_amdgcn_mfma_f32_16x16x32_bf16(sa[i], vb[j], oacc[i][j], 0, 0, 0);
    }
#pragma unroll
    for (int ks = 0; ks < 2; ks++) {
        shortx8 qa[2], ph[2], pl[2];
#pragma unroll
        for (int i = 0; i < 2; i++) qa[i] = read8(Qs, wr + i * 16 + lm, ks * 32 + q * 8);
#pragma unroll
        for (int j = 0; j < 2; j++) {
            ph[j] = read8(Phi, wc + j * 16 + lm, ks * 32 + q * 8);
            pl[j] = read8(Plo, wc + j * 16 + lm, ks * 32 + q * 8);
        }
#pragma unroll
        for (int i = 0; i < 2; i++)
#pragma unroll
            for (int j = 0; j < 2; j++) {
                oacc[i][j] = __builtin_amdgcn_mfma_f32_16x16x32_bf16(qa[i], ph[j], oacc[i][j], 0, 0, 0);
                oacc[i][j] = __builtin_amdgcn_mfma_f32_16x16x32_bf16(qa[i], pl[j], oacc[i][j], 0, 0, 0);
            }
    }
    const size_t tok0 = (size_t)(bh >> 3) * S_ + base;
    const int h = bh & 7;
#pragma unroll
    for (int i = 0; i < 2; i++)
#pragma unroll
        for (int j = 0; j < 2; j++)
#pragma unroll
            for (int r = 0; r < 4; r++) {
                int s = wr + i * 16 + q * 4 + r;
                int v = wc + j * 16 + lm;
                ctxb[(tok0 + s) * DM + h * 64 + v] = f2bf(gs[s] * oacc[i][j][r]);
            }
}

// ---------------------------------------------------------------------------
extern "C" void kernel_launch(void* const* d_in, const int* in_sizes, int n_in,
                              void* d_out, int out_size, void* d_ws, size_t ws_size,
                              hipStream_t stream) {
    const float* x       = (const float*)d_in[0];
    const float* Wvqkn_w = (const float*)d_in[1];
    const float* Wvqkn_b = (const float*)d_in[2];
    const float* out_w   = (const float*)d_in[3];
    const float* out_b   = (const float*)d_in[4];
    float* out = (float*)d_out;

    float* kvbuf = (float*)d_ws;                          // 16*32*4096 f32
    short* xb    = (short*)(kvbuf + (size_t)BH * NC * 4096);
    short* w1b   = xb   + (size_t)BS_ * DM;
    short* w2b   = w1b  + (size_t)NPAD1 * DM;
    short* ctxb  = w2b  + (size_t)DM * DM;
    short* qb    = ctxb + (size_t)BS_ * DM;
    short* kb    = qb   + (size_t)BH * S_ * 64;
    short* kTb   = kb   + (size_t)BH * S_ * 64;
    short* vTb   = kTb  + (size_t)BH * S_ * 64;
    float* gateb = (float*)(vTb + (size_t)BH * S_ * 64);

    convert_all<<<(int)((E1 + E2 + E3) / 8 / 256), 256, 0, stream>>>(
        x, Wvqkn_w, out_w, xb, w1b, w2b);

    gemm1_fused<<<dim3(NPAD1 / 128, BS_ / 64), 256, 0, stream>>>(
        xb, w1b, Wvqkn_b, qb, kb, kTb, vTb, gateb);

    chunk_kv_mfma<<<BH * NC, 256, 0, stream>>>(vTb, kTb, kvbuf);
    attn_mfma<<<BH * NC, 256, 0, stream>>>(qb, kb, vTb, gateb, kvbuf, ctxb);

    gemm_mfma64<<<dim3(DM / 128, BS_ / 64), 256, 0, stream>>>(ctxb, w2b, out_b, out, DM, DM);
}

// Round 5
// 109.662 us; speedup vs baseline: 2.5795x; 1.1051x over previous
//
#include <hip/hip_runtime.h>
#include <hip/hip_bf16.h>
#include <math.h>

#define B_    2
#define S_    2048
#define DM    512
#define H_    8
#define PROJ  1544
#define NPAD1 1664        // 13*128
#define CHK   64
#define NC    32
#define BS_   4096
#define BH    16

typedef __attribute__((ext_vector_type(8))) short shortx8;
typedef __attribute__((ext_vector_type(4))) short shortx4;
typedef __attribute__((ext_vector_type(4))) float floatx4;

#define GCAST(p) ((const __attribute__((address_space(1))) void*)(p))
#define LCAST(p) ((__attribute__((address_space(3))) void*)(p))

__device__ inline short f2bf(float f) {
    __hip_bfloat16 h = __float2bfloat16(f);
    return *(short*)&h;
}
__device__ inline float bf2f(short s) {
    __hip_bfloat16 h = *(__hip_bfloat16*)&s;
    return __bfloat162float(h);
}
// Read 8 contiguous bf16 (k mult of 8) from a 64-k-wide tile whose 16B groups
// are XOR-swizzled by row: element (row,k) lives at group (k>>3)^(row&7).
__device__ inline shortx8 read8(const short* buf, int row, int k) {
    return *(const shortx8*)&buf[row * 64 + ((((k >> 3) ^ (row & 7))) << 3)];
}

// ---------------------------------------------------------------------------
// One fused fp32->bf16 convert for x, W1 (zero row-pad to NPAD1), W2.
// ---------------------------------------------------------------------------
#define E1 ((size_t)BS_ * DM)
#define E2 ((size_t)NPAD1 * DM)
#define E3 ((size_t)DM * DM)
__global__ __launch_bounds__(256) void convert_all(const float* __restrict__ x,
                                                   const float* __restrict__ w1,
                                                   const float* __restrict__ w2,
                                                   short* __restrict__ xb,
                                                   short* __restrict__ w1b,
                                                   short* __restrict__ w2b) {
    size_t e = ((size_t)blockIdx.x * 256 + threadIdx.x) * 8;
    const float* src;
    short* dst;
    bool zero = false;
    if (e < E1) { src = x + e; dst = xb + e; }
    else if (e < E1 + E2) {
        size_t o = e - E1;
        dst = w1b + o;
        size_t row = o >> 9;
        if (row < PROJ) src = w1 + o; else { src = w1; zero = true; }
    } else if (e < E1 + E2 + E3) {
        size_t o = e - E1 - E2;
        src = w2 + o; dst = w2b + o;
    } else return;
    short out[8];
    if (zero) {
#pragma unroll
        for (int i = 0; i < 8; i++) out[i] = 0;
    } else {
        float4 f0 = *(const float4*)src;
        float4 f1 = *(const float4*)(src + 4);
        out[0] = f2bf(f0.x); out[1] = f2bf(f0.y); out[2] = f2bf(f0.z); out[3] = f2bf(f0.w);
        out[4] = f2bf(f1.x); out[5] = f2bf(f1.y); out[6] = f2bf(f1.z); out[7] = f2bf(f1.w);
    }
    *(shortx8*)dst = *(shortx8*)out;
}

// ---------------------------------------------------------------------------
// 64x128-tile, BK=64, XOR-swizzled bf16 MFMA GEMM.
// LDS: As 8KB + Bs 16KB. Fragment ds_read_b128s are bank-conflict-free:
// swizzled slot makes each 8-lane phase cover all 32 banks once.
// ---------------------------------------------------------------------------
__global__ __launch_bounds__(256) void gemm_mfma64(const short* __restrict__ A,
                                                   const short* __restrict__ Bw,
                                                   const float* __restrict__ bias,
                                                   float* __restrict__ C,
                                                   int N, int K) {
    __shared__ __align__(16) short As[64 * 64];
    __shared__ __align__(16) short Bs[128 * 64];
    const int tid  = threadIdx.x;
    const int wave = tid >> 6, lane = tid & 63;
    const int m0 = blockIdx.y * 64;
    const int n0 = blockIdx.x * 128;
    const int lrow = lane >> 3;                   // 0..7
    const int swz  = ((lane & 7) ^ lrow) << 3;    // global k-offset (elems)
    const int lm = lane & 15, q = lane >> 4;
    const int wc = wave * 32;
    floatx4 acc[4][2] = {};

    const short* gA0 = A  + (size_t)(m0 +      wave * 8 + lrow) * K + swz;
    const short* gA1 = A  + (size_t)(m0 + 32 + wave * 8 + lrow) * K + swz;
    const short* gB[4];
#pragma unroll
    for (int h = 0; h < 4; h++)
        gB[h] = Bw + (size_t)(n0 + h * 32 + wave * 8 + lrow) * K + swz;

    for (int k0 = 0; k0 < K; k0 += 64) {
        __builtin_amdgcn_global_load_lds(GCAST(gA0 + k0), LCAST(&As[(wave * 8) * 64]),        16, 0, 0);
        __builtin_amdgcn_global_load_lds(GCAST(gA1 + k0), LCAST(&As[(32 + wave * 8) * 64]),   16, 0, 0);
#pragma unroll
        for (int h = 0; h < 4; h++)
            __builtin_amdgcn_global_load_lds(GCAST(gB[h] + k0), LCAST(&Bs[(h * 32 + wave * 8) * 64]), 16, 0, 0);
        __syncthreads();
        shortx8 af[2][4], bw[2][2];
#pragma unroll
        for (int ks = 0; ks < 2; ks++) {
#pragma unroll
            for (int i = 0; i < 4; i++) af[ks][i] = read8(As, i * 16 + lm, ks * 32 + q * 8);
#pragma unroll
            for (int j = 0; j < 2; j++) bw[ks][j] = read8(Bs, wc + j * 16 + lm, ks * 32 + q * 8);
        }
#pragma unroll
        for (int ks = 0; ks < 2; ks++)
#pragma unroll
            for (int i = 0; i < 4; i++)
#pragma unroll
                for (int j = 0; j < 2; j++)
                    acc[i][j] = __builtin_amdgcn_mfma_f32_16x16x32_bf16(af[ks][i], bw[ks][j], acc[i][j], 0, 0, 0);
        __syncthreads();
    }
#pragma unroll
    for (int i = 0; i < 4; i++) {
        int rb = m0 + i * 16 + q * 4;
#pragma unroll
        for (int j = 0; j < 2; j++) {
            int col = n0 + wc + j * 16 + lm;
            float bv = bias[col];
#pragma unroll
            for (int r = 0; r < 4; r++)
                C[(size_t)(rb + r) * N + col] = acc[i][j][r] + bv;
        }
    }
}

// ---------------------------------------------------------------------------
// gemm1 (64x128, BK=64, swizzled) with fused epilogue producing q[bh][s][d],
// k[bh][t][d], kT[bh][d][s], vT[bh][v][s] (bf16), gate[bh][s] fp32.
// ---------------------------------------------------------------------------
__global__ __launch_bounds__(256) void gemm1_fused(const short* __restrict__ A,
                                                   const short* __restrict__ Bw,
                                                   const float* __restrict__ bias,
                                                   short* __restrict__ qb,
                                                   short* __restrict__ kb,
                                                   short* __restrict__ kTb,
                                                   short* __restrict__ vTb,
                                                   float* __restrict__ gateb) {
    __shared__ __align__(16) short As[64 * 64];
    __shared__ __align__(16) short Bs[128 * 64];
    const int K = DM;
    const int tid  = threadIdx.x;
    const int wave = tid >> 6, lane = tid & 63;
    const int m0 = blockIdx.y * 64;
    const int n0 = blockIdx.x * 128;
    const int lrow = lane >> 3;
    const int swz  = ((lane & 7) ^ lrow) << 3;
    const int lm = lane & 15, q = lane >> 4;
    const int wc = wave * 32;
    floatx4 acc[4][2] = {};

    const short* gA0 = A  + (size_t)(m0 +      wave * 8 + lrow) * K + swz;
    const short* gA1 = A  + (size_t)(m0 + 32 + wave * 8 + lrow) * K + swz;
    const short* gB[4];
#pragma unroll
    for (int h = 0; h < 4; h++)
        gB[h] = Bw + (size_t)(n0 + h * 32 + wave * 8 + lrow) * K + swz;

    for (int k0 = 0; k0 < K; k0 += 64) {
        __builtin_amdgcn_global_load_lds(GCAST(gA0 + k0), LCAST(&As[(wave * 8) * 64]),        16, 0, 0);
        __builtin_amdgcn_global_load_lds(GCAST(gA1 + k0), LCAST(&As[(32 + wave * 8) * 64]),   16, 0, 0);
#pragma unroll
        for (int h = 0; h < 4; h++)
            __builtin_amdgcn_global_load_lds(GCAST(gB[h] + k0), LCAST(&Bs[(h * 32 + wave * 8) * 64]), 16, 0, 0);
        __syncthreads();
        shortx8 af[2][4], bw[2][2];
#pragma unroll
        for (int ks = 0; ks < 2; ks++) {
#pragma unroll
            for (int i = 0; i < 4; i++) af[ks][i] = read8(As, i * 16 + lm, ks * 32 + q * 8);
#pragma unroll
            for (int j = 0; j < 2; j++) bw[ks][j] = read8(Bs, wc + j * 16 + lm, ks * 32 + q * 8);
        }
#pragma unroll
        for (int ks = 0; ks < 2; ks++)
#pragma unroll
            for (int i = 0; i < 4; i++)
#pragma unroll
                for (int j = 0; j < 2; j++)
                    acc[i][j] = __builtin_amdgcn_mfma_f32_16x16x32_bf16(af[ks][i], bw[ks][j], acc[i][j], 0, 0, 0);
        __syncthreads();
    }

    const int bIdx = m0 >> 11;
    const int bh0  = bIdx * H_;
#pragma unroll
    for (int i = 0; i < 4; i++) {
        int s0 = (m0 & (S_ - 1)) + i * 16 + q * 4;
#pragma unroll
        for (int j = 0; j < 2; j++) {
            int col = n0 + wc + j * 16 + lm;
            float bv = (col < PROJ) ? bias[col] : 0.f;
            float vals[4];
#pragma unroll
            for (int r = 0; r < 4; r++) vals[r] = acc[i][j][r] + bv;
            if (col < 512) {                       // v -> vT[bh][v][s]
                int h = col >> 6, vd = col & 63;
                short tmp[4];
#pragma unroll
                for (int r = 0; r < 4; r++) tmp[r] = f2bf(vals[r]);
                *(shortx4*)&vTb[((size_t)(bh0 + h) * 64 + vd) * S_ + s0] = *(shortx4*)tmp;
            } else if (col < 1024) {               // q -> q[bh][s][d]
                int h = (col >> 6) - 8, d = col & 63;
                size_t rb = ((size_t)(bh0 + h) * S_ + s0) * 64 + d;
#pragma unroll
                for (int r = 0; r < 4; r++) qb[rb + (size_t)r * 64] = f2bf(vals[r]);
            } else if (col < 1536) {               // k -> k[bh][t][d] and kT[bh][d][t]
                int h = (col >> 6) - 16, d = col & 63;
                size_t rb = ((size_t)(bh0 + h) * S_ + s0) * 64 + d;
                short tmp[4];
#pragma unroll
                for (int r = 0; r < 4; r++) { tmp[r] = f2bf(vals[r]); kb[rb + (size_t)r * 64] = tmp[r]; }
                *(shortx4*)&kTb[((size_t)(bh0 + h) * 64 + d) * S_ + s0] = *(shortx4*)tmp;
            } else if (col < PROJ) {               // n -> gate[bh][s]
                int h = col - 1536;
                float g[4];
#pragma unroll
                for (int r = 0; r < 4; r++) g[r] = __expf(-__expf(vals[r]));
                *(float4*)&gateb[(size_t)(bh0 + h) * S_ + s0] = make_float4(g[0], g[1], g[2], g[3]);
            }
        }
    }
}

// ---------------------------------------------------------------------------
// Per-chunk state via MFMA: U[v][d] = sum_{s in chunk} V[s][v] * K[s][d]
// ---------------------------------------------------------------------------
__global__ __launch_bounds__(256) void chunk_kv_mfma(const short* __restrict__ vTb,
                                                     const short* __restrict__ kTb,
                                                     float* __restrict__ kvbuf) {
    __shared__ __align__(16) short VT[64 * 64];
    __shared__ __align__(16) short KT[64 * 64];
    const int blk = blockIdx.x;
    const int c = blk & (NC - 1), bh = blk >> 5;
    const int base = c * CHK;
    const int tid = threadIdx.x, wave = tid >> 6, lane = tid & 63;
    const int lrow = lane >> 3, lgrp = lane & 7;

#pragma unroll
    for (int half = 0; half < 2; half++) {
        int v0 = wave * 8 + half * 32;
        int row = v0 + lrow;
        int gcol = ((lgrp ^ (row & 7)) << 3);
        __builtin_amdgcn_global_load_lds(GCAST(vTb + ((size_t)(bh * 64 + row)) * S_ + base + gcol),
                                         LCAST(&VT[v0 * 64]), 16, 0, 0);
        __builtin_amdgcn_global_load_lds(GCAST(kTb + ((size_t)(bh * 64 + row)) * S_ + base + gcol),
                                         LCAST(&KT[v0 * 64]), 16, 0, 0);
    }
    __syncthreads();

    const int lm = lane & 15, q = lane >> 4;
    const int wr = (wave >> 1) * 32, wc = (wave & 1) * 32;
    floatx4 acc[2][2] = {};
#pragma unroll
    for (int ks = 0; ks < 2; ks++) {
        shortx8 a[2], b2[2];
#pragma unroll
        for (int i = 0; i < 2; i++) a[i]  = read8(VT, wr + i * 16 + lm, ks * 32 + q * 8);
#pragma unroll
        for (int j = 0; j < 2; j++) b2[j] = read8(KT, wc + j * 16 + lm, ks * 32 + q * 8);
#pragma unroll
        for (int i = 0; i < 2; i++)
#pragma unroll
            for (int j = 0; j < 2; j++)
                acc[i][j] = __builtin_amdgcn_mfma_f32_16x16x32_bf16(a[i], b2[j], acc[i][j], 0, 0, 0);
    }
    float* outp = kvbuf + ((size_t)blk << 12);
#pragma unroll
    for (int i = 0; i < 2; i++)
#pragma unroll
        for (int j = 0; j < 2; j++)
#pragma unroll
            for (int r = 0; r < 4; r++)
                outp[(wr + i * 16 + q * 4 + r) * 64 + wc + j * 16 + lm] = acc[i][j][r];
}

// ---------------------------------------------------------------------------
// Group-of-4 exclusive prefix over chunk states:
// kvg[bh][g][e] = sum_{c < 4g} U[c][e],  g = 0..7.
// grid = 16 bh x 16 segs = 256 blocks.
// ---------------------------------------------------------------------------
__global__ __launch_bounds__(256) void scan_groups(const float* __restrict__ kvbuf,
                                                   float* __restrict__ kvg) {
    const int blk = blockIdx.x;
    const int bh = blk >> 4, seg = blk & 15;
    const int e = seg * 256 + threadIdx.x;
    const float* src = kvbuf + (((size_t)bh * NC) << 12) + e;
    float* dst = kvg + (((size_t)bh * 8) << 12) + e;
    float run = 0.f;
#pragma unroll
    for (int g = 0; g < 8; g++) {
        dst[(size_t)g << 12] = run;
#pragma unroll
        for (int cc = 0; cc < 4; cc++)
            run += src[(size_t)(g * 4 + cc) << 12];
    }
}

// ---------------------------------------------------------------------------
// MFMA attention chunk. Prefix = kvg[c>>2] + <=3 chunk states (fp32).
// ---------------------------------------------------------------------------
__global__ __launch_bounds__(256) void attn_mfma(const short* __restrict__ qb,
                                                 const short* __restrict__ kb,
                                                 const short* __restrict__ vTb,
                                                 const float* __restrict__ gateb,
                                                 const float* __restrict__ kvbuf,
                                                 const float* __restrict__ kvg,
                                                 short* __restrict__ ctxb) {
    __shared__ __align__(16) short Qs[64 * 64];
    __shared__ __align__(16) short Ks[64 * 64];
    __shared__ __align__(16) short VTs[64 * 64];
    __shared__ __align__(16) short Phi[64 * 64];
    __shared__ __align__(16) short Plo[64 * 64];
    __shared__ __align__(16) short Sb[64 * 72];
    __shared__ float gs[64];
    const int blk = blockIdx.x;
    const int bh = blk & (BH - 1);
    const int c  = (NC - 1) - (blk >> 4);
    const int base = c * CHK;
    const int tid = threadIdx.x, wave = tid >> 6, lane = tid & 63;
    const int lrow = lane >> 3, lgrp = lane & 7;

#pragma unroll
    for (int half = 0; half < 2; half++) {
        int v0 = wave * 8 + half * 32;
        int row = v0 + lrow;
        int gcol = ((lgrp ^ (row & 7)) << 3);
        __builtin_amdgcn_global_load_lds(GCAST(qb + ((size_t)bh * S_ + base + row) * 64 + gcol),
                                         LCAST(&Qs[v0 * 64]), 16, 0, 0);
        __builtin_amdgcn_global_load_lds(GCAST(kb + ((size_t)bh * S_ + base + row) * 64 + gcol),
                                         LCAST(&Ks[v0 * 64]), 16, 0, 0);
        __builtin_amdgcn_global_load_lds(GCAST(vTb + ((size_t)(bh * 64 + row)) * S_ + base + gcol),
                                         LCAST(&VTs[v0 * 64]), 16, 0, 0);
    }

    // Prefix = group prefix + <=3 preceding chunks within the group (fp32).
    float pacc[16];
    {
        const float* gp = kvg + (((size_t)bh * 8 + (c >> 2)) << 12) + tid;
#pragma unroll
        for (int it = 0; it < 16; it++) pacc[it] = gp[it * 256];
        const float* kvb = kvbuf + (((size_t)bh * NC) << 12) + tid;
        for (int cp = c & ~3; cp < c; cp++) {
            const float* p = kvb + ((size_t)cp << 12);
#pragma unroll
            for (int it = 0; it < 16; it++) pacc[it] += p[it * 256];
        }
    }
#pragma unroll
    for (int it = 0; it < 16; it++) {
        int idx = it * 256 + tid;
        int v = idx >> 6, d = idx & 63;
        float f = pacc[it];
        short hi = f2bf(f);
        short lo = f2bf(f - bf2f(hi));
        int sw = v * 64 + (((d >> 3) ^ (v & 7)) << 3) + (d & 7);
        Phi[sw] = hi; Plo[sw] = lo;
    }
    if (tid < 64) gs[tid] = gateb[(size_t)bh * S_ + base + tid];
    __syncthreads();

    const int lm = lane & 15, q = lane >> 4;
    const int wr = (wave >> 1) * 32, wc = (wave & 1) * 32;

    // Phase 1: S quadrant = Q K^T, causal mask, -> Sb bf16
    floatx4 sacc[2][2] = {};
#pragma unroll
    for (int ks = 0; ks < 2; ks++) {
        shortx8 qa[2], kf[2];
#pragma unroll
        for (int i = 0; i < 2; i++) qa[i] = read8(Qs, wr + i * 16 + lm, ks * 32 + q * 8);
#pragma unroll
        for (int j = 0; j < 2; j++) kf[j] = read8(Ks, wc + j * 16 + lm, ks * 32 + q * 8);
#pragma unroll
        for (int i = 0; i < 2; i++)
#pragma unroll
            for (int j = 0; j < 2; j++)
                sacc[i][j] = __builtin_amdgcn_mfma_f32_16x16x32_bf16(qa[i], kf[j], sacc[i][j], 0, 0, 0);
    }
#pragma unroll
    for (int i = 0; i < 2; i++)
#pragma unroll
        for (int j = 0; j < 2; j++)
#pragma unroll
            for (int r = 0; r < 4; r++) {
                int s = wr + i * 16 + q * 4 + r;
                int t = wc + j * 16 + lm;
                Sb[s * 72 + t] = f2bf(t <= s ? sacc[i][j][r] : 0.f);
            }
    __syncthreads();

    // Phase 2: O = S.V + Q.(Phi+Plo)
    floatx4 oacc[2][2] = {};
#pragma unroll
    for (int ks = 0; ks < 2; ks++) {
        shortx8 sa[2], vb[2];
#pragma unroll
        for (int i = 0; i < 2; i++)
            sa[i] = *(const shortx8*)&Sb[(wr + i * 16 + lm) * 72 + ks * 32 + q * 8];
#pragma unroll
        for (int j = 0; j < 2; j++) vb[j] = read8(VTs, wc + j * 16 + lm, ks * 32 + q * 8);
#pragma unroll
        for (int i = 0; i < 2; i++)
#pragma unroll
            for (int j = 0; j < 2; j++)
                oacc[i][j] = __builtin_amdgcn_mfma_f32_16x16x32_bf16(sa[i], vb[j], oacc[i][j], 0, 0, 0);
    }
#pragma unroll
    for (int ks = 0; ks < 2; ks++) {
        shortx8 qa[2], ph[2], pl[2];
#pragma unroll
        for (int i = 0; i < 2; i++) qa[i] = read8(Qs, wr + i * 16 + lm, ks * 32 + q * 8);
#pragma unroll
        for (int j = 0; j < 2; j++) {
            ph[j] = read8(Phi, wc + j * 16 + lm, ks * 32 + q * 8);
            pl[j] = read8(Plo, wc + j * 16 + lm, ks * 32 + q * 8);
        }
#pragma unroll
        for (int i = 0; i < 2; i++)
#pragma unroll
            for (int j = 0; j < 2; j++) {
                oacc[i][j] = __builtin_amdgcn_mfma_f32_16x16x32_bf16(qa[i], ph[j], oacc[i][j], 0, 0, 0);
                oacc[i][j] = __builtin_amdgcn_mfma_f32_16x16x32_bf16(qa[i], pl[j], oacc[i][j], 0, 0, 0);
            }
    }
    const size_t tok0 = (size_t)(bh >> 3) * S_ + base;
    const int h = bh & 7;
#pragma unroll
    for (int i = 0; i < 2; i++)
#pragma unroll
        for (int j = 0; j < 2; j++)
#pragma unroll
            for (int r = 0; r < 4; r++) {
                int s = wr + i * 16 + q * 4 + r;
                int v = wc + j * 16 + lm;
                ctxb[(tok0 + s) * DM + h * 64 + v] = f2bf(gs[s] * oacc[i][j][r]);
            }
}

// ---------------------------------------------------------------------------
extern "C" void kernel_launch(void* const* d_in, const int* in_sizes, int n_in,
                              void* d_out, int out_size, void* d_ws, size_t ws_size,
                              hipStream_t stream) {
    const float* x       = (const float*)d_in[0];
    const float* Wvqkn_w = (const float*)d_in[1];
    const float* Wvqkn_b = (const float*)d_in[2];
    const float* out_w   = (const float*)d_in[3];
    const float* out_b   = (const float*)d_in[4];
    float* out = (float*)d_out;

    float* kvbuf = (float*)d_ws;                          // 16*32*4096 f32
    float* kvg   = kvbuf + (size_t)BH * NC * 4096;        // 16*8*4096 f32
    short* xb    = (short*)(kvg + (size_t)BH * 8 * 4096);
    short* w1b   = xb   + (size_t)BS_ * DM;
    short* w2b   = w1b  + (size_t)NPAD1 * DM;
    short* ctxb  = w2b  + (size_t)DM * DM;
    short* qb    = ctxb + (size_t)BS_ * DM;
    short* kb    = qb   + (size_t)BH * S_ * 64;
    short* kTb   = kb   + (size_t)BH * S_ * 64;
    short* vTb   = kTb  + (size_t)BH * S_ * 64;
    float* gateb = (float*)(vTb + (size_t)BH * S_ * 64);

    convert_all<<<(int)((E1 + E2 + E3) / 8 / 256), 256, 0, stream>>>(
        x, Wvqkn_w, out_w, xb, w1b, w2b);

    gemm1_fused<<<dim3(NPAD1 / 128, BS_ / 64), 256, 0, stream>>>(
        xb, w1b, Wvqkn_b, qb, kb, kTb, vTb, gateb);

    chunk_kv_mfma<<<BH * NC, 256, 0, stream>>>(vTb, kTb, kvbuf);
    scan_groups<<<BH * 16, 256, 0, stream>>>(kvbuf, kvg);
    attn_mfma<<<BH * NC, 256, 0, stream>>>(qb, kb, vTb, gateb, kvbuf, kvg, ctxb);

    gemm_mfma64<<<dim3(DM / 128, BS_ / 64), 256, 0, stream>>>(ctxb, w2b, out_b, out, DM, DM);
}